// Round 1
// baseline (1644.353 us; speedup 1.0000x reference)
//
#include <hip/hip_runtime.h>
#include <hip/hip_bf16.h>

#define N_IN   200000
#define N_OUT  600000
#define KOFF   27
#define PPAIR  150000
#define C      96
#define BN_EPS 1e-5f

using bf16x8 = __attribute__((ext_vector_type(8))) __bf16;
using f32x4  = __attribute__((ext_vector_type(4))) float;

static __device__ __forceinline__ unsigned short f2b(float x) {
    __hip_bfloat16 h = __float2bfloat16(x);
    return *reinterpret_cast<unsigned short*>(&h);
}

// Convert feats fp32 -> bf16, 8 elems/thread. 19,200,000 elems = 9375*256*8.
__global__ void cvt_feats(const float* __restrict__ src, unsigned short* __restrict__ dst) {
    int t = blockIdx.x * 256 + threadIdx.x;
    const float4* s4 = (const float4*)src;
    float4 a = s4[2 * t], b = s4[2 * t + 1];
    union { unsigned short u[8]; uint4 v; } r;
    r.u[0] = f2b(a.x); r.u[1] = f2b(a.y); r.u[2] = f2b(a.z); r.u[3] = f2b(a.w);
    r.u[4] = f2b(b.x); r.u[5] = f2b(b.y); r.u[6] = f2b(b.z); r.u[7] = f2b(b.w);
    ((uint4*)dst)[t] = r.v;
}

// weight [k][c_in][c_out] fp32 -> wt [k][c_out][c_in] bf16 (transposed for B frags)
__global__ void cvt_w(const float* __restrict__ w, unsigned short* __restrict__ wt) {
    int t = blockIdx.x * 256 + threadIdx.x;   // 248832 = 972*256 exactly
    int k = t / 9216;
    int rem = t - k * 9216;
    int o = rem / 96;
    int i = rem - o * 96;
    wt[t] = f2b(w[k * 9216 + i * 96 + o]);
}

// Gather -> 64x96 @ 96x96 bf16 MFMA -> atomic scatter-add.
__global__ __launch_bounds__(256, 2) void gms(
    const unsigned short* __restrict__ fb,   // feats bf16 [N_IN][96]
    const unsigned short* __restrict__ wt,   // weight bf16 [27][96(out)][96(in)]
    const int* __restrict__ in_idx,
    const int* __restrict__ out_idx,
    float* __restrict__ out)
{
    __shared__ unsigned short As[64][104];   // pad 96->104: 52-word stride, 2-way bank alias = free
    __shared__ unsigned short Bs[96][104];
    __shared__ int s_oidx[64];

    const int t    = threadIdx.x;
    const int k    = blockIdx.y;
    const int row0 = blockIdx.x * 64;
    const long kp  = (long)k * PPAIR;

    if (t < 64) {
        int p = row0 + t;
        s_oidx[t] = (p < PPAIR) ? out_idx[kp + p] : -1;
    }
    // stage A: 64 rows x 12 chunks of 16B
    for (int i = t; i < 64 * 12; i += 256) {
        int row = i / 12, ch = i - row * 12;
        int p = row0 + row; if (p >= PPAIR) p = PPAIR - 1;
        int g = in_idx[kp + p];
        *(uint4*)(&As[row][ch * 8]) = *(const uint4*)(fb + (size_t)g * 96 + ch * 8);
    }
    // stage B: 96 rows x 12 chunks
    {
        const uint4* wsrc = (const uint4*)(wt + (size_t)k * 9216);
        for (int i = t; i < 96 * 12; i += 256) {
            int row = i / 12, ch = i - row * 12;
            *(uint4*)(&Bs[row][ch * 8]) = wsrc[row * 12 + ch];
        }
    }
    __syncthreads();

    const int wave = t >> 6, lane = t & 63;
    const int quad = lane >> 4, l16 = lane & 15;
    const int mrow = wave * 16 + l16;

    f32x4 acc[6];
#pragma unroll
    for (int n = 0; n < 6; n++) acc[n] = (f32x4){0.f, 0.f, 0.f, 0.f};

#pragma unroll
    for (int kk = 0; kk < 3; kk++) {
        int kb = kk * 32 + quad * 8;
        bf16x8 a = *(const bf16x8*)(&As[mrow][kb]);
#pragma unroll
        for (int n = 0; n < 6; n++) {
            bf16x8 b = *(const bf16x8*)(&Bs[n * 16 + l16][kb]);
            acc[n] = __builtin_amdgcn_mfma_f32_16x16x32_bf16(a, b, acc[n], 0, 0, 0);
        }
    }

    // scatter-add: D layout col=lane&15, row=quad*4+reg
#pragma unroll
    for (int r = 0; r < 4; r++) {
        int lr = wave * 16 + quad * 4 + r;
        int o = s_oidx[lr];
        if (o >= 0) {
            float* orow = out + (size_t)o * 96;
#pragma unroll
            for (int n = 0; n < 6; n++)
                atomicAdd(orow + n * 16 + l16, acc[n][r]);
        }
    }
}

// Per-channel sum & sumsq. gridDim*blockDim = 258048 (multiple of 24) so each
// thread's float4 channel-group g = t%24 is fixed across the grid-stride loop.
__global__ void bn_stats(const float* __restrict__ out, float* __restrict__ sums) {
    int t = blockIdx.x * 256 + threadIdx.x;
    int g = t % 24;
    float s0 = 0, s1 = 0, s2 = 0, s3 = 0, q0 = 0, q1 = 0, q2 = 0, q3 = 0;
    const float4* o4 = (const float4*)out;
    for (long f = t; f < 14400000L; f += 258048) {
        float4 v = o4[f];
        s0 += v.x; s1 += v.y; s2 += v.z; s3 += v.w;
        q0 += v.x * v.x; q1 += v.y * v.y; q2 += v.z * v.z; q3 += v.w * v.w;
    }
    __shared__ float ls[192];
    if (threadIdx.x < 192) ls[threadIdx.x] = 0.f;
    __syncthreads();
    atomicAdd(&ls[g * 4 + 0], s0); atomicAdd(&ls[g * 4 + 1], s1);
    atomicAdd(&ls[g * 4 + 2], s2); atomicAdd(&ls[g * 4 + 3], s3);
    atomicAdd(&ls[96 + g * 4 + 0], q0); atomicAdd(&ls[96 + g * 4 + 1], q1);
    atomicAdd(&ls[96 + g * 4 + 2], q2); atomicAdd(&ls[96 + g * 4 + 3], q3);
    __syncthreads();
    if (threadIdx.x < 192) atomicAdd(&sums[threadIdx.x], ls[threadIdx.x]);
}

// sums[0..95] -> scale, sums[96..191] -> shift
__global__ void bn_final(float* __restrict__ sums, const float* __restrict__ gamma,
                         const float* __restrict__ beta) {
    int c = threadIdx.x;
    if (c < 96) {
        float mean = sums[c] * (1.0f / (float)N_OUT);
        float var  = sums[96 + c] * (1.0f / (float)N_OUT) - mean * mean;
        float inv  = rsqrtf(var + BN_EPS);
        float sc   = inv * gamma[c];
        sums[c]      = sc;
        sums[96 + c] = beta[c] - mean * sc;
    }
}

__global__ void bn_apply(float* __restrict__ out, const float* __restrict__ sums) {
    int t = blockIdx.x * 256 + threadIdx.x;
    int g = t % 24;
    float sc0 = sums[g * 4 + 0], sc1 = sums[g * 4 + 1];
    float sc2 = sums[g * 4 + 2], sc3 = sums[g * 4 + 3];
    float sh0 = sums[96 + g * 4 + 0], sh1 = sums[96 + g * 4 + 1];
    float sh2 = sums[96 + g * 4 + 2], sh3 = sums[96 + g * 4 + 3];
    float4* o4 = (float4*)out;
    for (long f = t; f < 14400000L; f += 258048) {
        float4 v = o4[f];
        v.x = fmaxf(v.x * sc0 + sh0, 0.f);
        v.y = fmaxf(v.y * sc1 + sh1, 0.f);
        v.z = fmaxf(v.z * sc2 + sh2, 0.f);
        v.w = fmaxf(v.w * sc3 + sh3, 0.f);
        o4[f] = v;
    }
}

extern "C" void kernel_launch(void* const* d_in, const int* in_sizes, int n_in,
                              void* d_out, int out_size, void* d_ws, size_t ws_size,
                              hipStream_t stream) {
    const float* feats  = (const float*)d_in[0];
    const int* in_idx   = (const int*)d_in[1];
    const int* out_idx  = (const int*)d_in[2];
    const float* weight = (const float*)d_in[3];
    const float* gamma  = (const float*)d_in[4];
    const float* beta   = (const float*)d_in[5];
    float* out = (float*)d_out;

    char* ws = (char*)d_ws;
    unsigned short* fb = (unsigned short*)ws;                          // 38,400,000 B
    unsigned short* wt = (unsigned short*)(ws + 38400000);             //    497,664 B
    float* sums        = (float*)(ws + 38400000 + 497664);             //        768 B

    hipMemsetAsync(d_out, 0, (size_t)out_size * sizeof(float), stream);
    hipMemsetAsync(sums, 0, 192 * sizeof(float), stream);

    cvt_feats<<<9375, 256, 0, stream>>>(feats, fb);
    cvt_w<<<972, 256, 0, stream>>>(weight, wt);
    gms<<<dim3(2344, KOFF), 256, 0, stream>>>(fb, wt, in_idx, out_idx, out);
    bn_stats<<<1008, 256, 0, stream>>>(out, sums);
    bn_final<<<1, 128, 0, stream>>>(sums, gamma, beta);
    bn_apply<<<1008, 256, 0, stream>>>(out, sums);
}